// Round 6
// baseline (751.715 us; speedup 1.0000x reference)
//
#include <hip/hip_runtime.h>

#define N_NODES 50000
#define N_EDGES 800000
#define F_IN 56
#define F_PAD 64
#define F_OUT 256
#define NB 64                 // nodes per k_final block
#define ELL_W 64              // slots per node; deg+1 max ~37 for Poisson(16)
#define NSLICE (N_NODES * 16) // elements per 16-feature slice (3.2 MB fp32)

typedef float f32x4 __attribute__((ext_vector_type(4)));  // NT-store-compatible

// ---- fill: degree count + ELL placement in ONE atomic pass ----------------

__global__ void k_fill(const int* __restrict__ ei, int* __restrict__ cnt,
                       unsigned short* __restrict__ ell) {
  int e = blockIdx.x * blockDim.x + threadIdx.x;
  if (e >= N_EDGES) return;
  int s = ei[e];
  int d = ei[N_EDGES + e];
  int pos = atomicAdd(&cnt[d], 1);
  ell[(d << 6) + pos] = (unsigned short)s;
}

// ---- dinv + deg + self-loop slot -------------------------------------------

__global__ void k_dinv(const int* __restrict__ cnt, float* __restrict__ dinv,
                       int* __restrict__ deg, unsigned short* __restrict__ ell) {
  int i = blockIdx.x * blockDim.x + threadIdx.x;
  if (i >= N_NODES) return;
  int c = cnt[i];
  dinv[i] = rsqrtf((float)(c + 1));
  deg[i] = c + 1;
  ell[(i << 6) + c] = (unsigned short)i;  // self loop in last used slot
}

// ---- per-slot weights + pad sanitize (coalesced) ---------------------------

__global__ void k_wfill(const int* __restrict__ deg, unsigned short* __restrict__ ell,
                        const float* __restrict__ dinv, float* __restrict__ well) {
  int i = blockIdx.x * blockDim.x + threadIdx.x;  // N*64 threads
  int node = i >> 6, slot = i & 63;
  int d = deg[node];
  float w = 0.f;
  if (slot < d) {
    w = dinv[ell[i]] * dinv[node];   // self-loop slot gives dinv^2
  } else {
    ell[i] = (unsigned short)node;   // safe in-bounds src, weight 0
  }
  well[i] = w;
}

// ---- feature init into SLICED layout: h[s][node][16], ones in col 56 ------

__global__ void k_loadx(const float* __restrict__ x, float* __restrict__ h) {
  int i = blockIdx.x * blockDim.x + threadIdx.x;  // N*64 threads
  int node = i >> 6, f = i & 63;
  float v = 0.f;
  if (f < F_IN) v = x[node * F_IN + f];
  else if (f == F_IN) v = 1.f;
  int s = f >> 4, fi = f & 15;
  h[(size_t)s * NSLICE + ((size_t)node << 4) + fi] = v;
}

// ---- one hop on one 16-feature slice ---------------------------------------
// wave = 4 nodes x 4 edge-subgroups x 4 feature-lanes; lane loads float4 (64B
// row = 4 lanes). One gather instr = 16 x 64B lines = 1KB. Meta NT-streamed;
// hout NT-stored so the L2-resident src slice stays hot.

__global__ __launch_bounds__(256) void k_hop(const float* __restrict__ hin,
                                             float* __restrict__ hout,
                                             const int* __restrict__ deg,
                                             const unsigned short* __restrict__ ell,
                                             const float* __restrict__ well,
                                             float* __restrict__ vsave) {
  int t = blockIdx.x * blockDim.x + threadIdx.x;   // N*16 threads
  int wave = t >> 6, lane = t & 63;
  int node = (wave << 2) + (lane >> 4);
  int m = lane & 15, sub = m >> 2, q = m & 3;
  int d = deg[node];
  int ngroups = (d + 3) >> 2;                      // pads have w=0
  const unsigned short* row = ell + ((size_t)node << 6) + sub;
  const float* wrow = well + ((size_t)node << 6) + sub;
  float4 acc = make_float4(0.f, 0.f, 0.f, 0.f);
  int g = 0;
  for (; g + 2 <= ngroups; g += 2) {
    int   s0 = __builtin_nontemporal_load(row + (g << 2));
    float w0 = __builtin_nontemporal_load(wrow + (g << 2));
    int   s1 = __builtin_nontemporal_load(row + (g << 2) + 4);
    float w1 = __builtin_nontemporal_load(wrow + (g << 2) + 4);
    float4 a0 = *(const float4*)(hin + ((size_t)s0 << 4) + (q << 2));
    float4 a1 = *(const float4*)(hin + ((size_t)s1 << 4) + (q << 2));
    acc.x = fmaf(w0, a0.x, acc.x);
    acc.y = fmaf(w0, a0.y, acc.y);
    acc.z = fmaf(w0, a0.z, acc.z);
    acc.w = fmaf(w0, a0.w, acc.w);
    acc.x = fmaf(w1, a1.x, acc.x);
    acc.y = fmaf(w1, a1.y, acc.y);
    acc.z = fmaf(w1, a1.z, acc.z);
    acc.w = fmaf(w1, a1.w, acc.w);
  }
  if (g < ngroups) {
    int   s0 = __builtin_nontemporal_load(row + (g << 2));
    float w0 = __builtin_nontemporal_load(wrow + (g << 2));
    float4 a0 = *(const float4*)(hin + ((size_t)s0 << 4) + (q << 2));
    acc.x = fmaf(w0, a0.x, acc.x);
    acc.y = fmaf(w0, a0.y, acc.y);
    acc.z = fmaf(w0, a0.z, acc.z);
    acc.w = fmaf(w0, a0.w, acc.w);
  }
  // butterfly across the 4 edge subgroups (xor 4, xor 8 stay within 16 lanes)
  acc.x += __shfl_xor(acc.x, 4);
  acc.y += __shfl_xor(acc.y, 4);
  acc.z += __shfl_xor(acc.z, 4);
  acc.w += __shfl_xor(acc.w, 4);
  acc.x += __shfl_xor(acc.x, 8);
  acc.y += __shfl_xor(acc.y, 8);
  acc.z += __shfl_xor(acc.z, 8);
  acc.w += __shfl_xor(acc.w, 8);

  if (m < 4) {  // lane m stores feature quad m (all lanes hold their q's total)
    f32x4 av; av.x = acc.x; av.y = acc.y; av.z = acc.z; av.w = acc.w;
    __builtin_nontemporal_store(av, (f32x4*)(hout + ((size_t)node << 4) + (m << 2)));
  }
  if (vsave != nullptr && m == 2) vsave[node] = acc.x;  // slice-3 feat 8 = col 56
}

// ---- collapse weights: M = W1W2W3W4; c1=b1'W2W3W4; c2=b2'W3W4; c3=b3'W4+b4

__global__ void k_weights(const float* __restrict__ W1, const float* __restrict__ b1,
                          const float* __restrict__ W2, const float* __restrict__ b2,
                          const float* __restrict__ W3, const float* __restrict__ b3,
                          const float* __restrict__ W4, const float* __restrict__ b4,
                          float* __restrict__ Mw, float* __restrict__ c1,
                          float* __restrict__ c2, float* __restrict__ c3) {
  __shared__ float t1[64], t2[64], t3[64];
  int m = blockIdx.x, tid = threadIdx.x;
  if (m < F_IN) {  // row m of M: ((W1[m,:]W2)W3)W4
    if (tid < 64) {
      float a = 0.f;
      for (int k = 0; k < 64; ++k) a = fmaf(W1[m * 64 + k], W2[k * 64 + tid], a);
      t1[tid] = a;
    }
    __syncthreads();
    if (tid < 64) {
      float a = 0.f;
      for (int k = 0; k < 64; ++k) a = fmaf(t1[k], W3[k * 64 + tid], a);
      t2[tid] = a;
    }
    __syncthreads();
    {
      float a = 0.f;
      for (int k = 0; k < 64; ++k) a = fmaf(t2[k], W4[k * 256 + tid], a);
      Mw[m * 256 + tid] = a;
    }
  } else {  // bias chains
    if (tid < 64) {
      float a = 0.f;
      for (int k = 0; k < 64; ++k) a = fmaf(b1[k], W2[k * 64 + tid], a);
      t1[tid] = a;
    }
    __syncthreads();
    if (tid < 64) {
      float a = 0.f, b = 0.f;
      for (int k = 0; k < 64; ++k) {
        float w3 = W3[k * 64 + tid];
        a = fmaf(t1[k], w3, a);
        b = fmaf(b2[k], w3, b);
      }
      t2[tid] = a; t3[tid] = b;
    }
    __syncthreads();
    {
      float a = 0.f, b = 0.f, c = 0.f;
      for (int k = 0; k < 64; ++k) {
        float w4 = W4[k * 256 + tid];
        a = fmaf(t2[k], w4, a);
        b = fmaf(t3[k], w4, b);
        c = fmaf(b3[k], w4, c);
      }
      c1[tid] = a; c2[tid] = b; c3[tid] = c + b4[tid];
    }
  }
}

// ---- epilogue: out = y@M + v6*c1 + v3*c2 + c3 ------------------------------
// thread j owns output col j; M[:,j] in registers; y rows broadcast via LDS.
// y arrives in sliced layout: y[s*NSLICE + node*16 + fi].

__global__ __launch_bounds__(256) void k_final(const float* __restrict__ y,
                                               const float* __restrict__ v3,
                                               const float* __restrict__ v6,
                                               const float* __restrict__ Mw,
                                               const float* __restrict__ c1,
                                               const float* __restrict__ c2,
                                               const float* __restrict__ c3,
                                               float* __restrict__ out) {
  __shared__ float4 yl[NB][16];          // 16.5 KB
  __shared__ float v3l[NB], v6l[NB];
  int tid = threadIdx.x;
  int j = tid;                           // output column

  float4 Mreg[14];                       // M[:, j]
#pragma unroll
  for (int k4 = 0; k4 < 14; ++k4) {
    Mreg[k4].x = Mw[(k4 * 4 + 0) * F_OUT + j];
    Mreg[k4].y = Mw[(k4 * 4 + 1) * F_OUT + j];
    Mreg[k4].z = Mw[(k4 * 4 + 2) * F_OUT + j];
    Mreg[k4].w = Mw[(k4 * 4 + 3) * F_OUT + j];
  }
  float C1 = c1[j], C2 = c2[j], C3 = c3[j];

  int n0 = blockIdx.x * NB;
  int lim = min(NB, N_NODES - n0);
  for (int i = tid; i < lim * 16; i += 256) {
    int nn = i >> 4, q = i & 15;         // 16 float4 chunks = 64 features
    int s = q >> 2, qq = q & 3;
    yl[nn][q] = *(const float4*)(y + (size_t)s * NSLICE +
                                 ((size_t)(n0 + nn) << 4) + qq * 4);
  }
  if (tid < lim) { v3l[tid] = v3[n0 + tid]; v6l[tid] = v6[n0 + tid]; }
  __syncthreads();

  for (int nn = 0; nn < lim; ++nn) {
    float acc = fmaf(v6l[nn], C1, fmaf(v3l[nn], C2, C3));
#pragma unroll
    for (int k4 = 0; k4 < 14; ++k4) {    // only first 56 features carry data
      float4 yv = yl[nn][k4];
      acc = fmaf(yv.x, Mreg[k4].x, acc);
      acc = fmaf(yv.y, Mreg[k4].y, acc);
      acc = fmaf(yv.z, Mreg[k4].z, acc);
      acc = fmaf(yv.w, Mreg[k4].w, acc);
    }
    out[(size_t)(n0 + nn) * F_OUT + j] = acc;
  }
}

// ---- launch ----------------------------------------------------------------

extern "C" void kernel_launch(void* const* d_in, const int* in_sizes, int n_in,
                              void* d_out, int out_size, void* d_ws, size_t ws_size,
                              hipStream_t stream) {
  const float* x  = (const float*)d_in[0];
  const int*   ei = (const int*)d_in[1];
  const float* W1 = (const float*)d_in[2];
  const float* b1 = (const float*)d_in[3];
  const float* W2 = (const float*)d_in[4];
  const float* b2 = (const float*)d_in[5];
  const float* W3 = (const float*)d_in[6];
  const float* b3 = (const float*)d_in[7];
  const float* W4 = (const float*)d_in[8];
  const float* b4 = (const float*)d_in[9];
  float* out = (float*)d_out;

  char* ws = (char*)d_ws;
  size_t off = 0;
  auto take = [&](size_t bytes) -> void* {
    void* p = ws + off;
    off += (bytes + 255) & ~(size_t)255;
    return p;
  };
  int*            cnt   = (int*)take((size_t)N_NODES * 4);
  int*            deg   = (int*)take((size_t)N_NODES * 4);
  float*          dinv  = (float*)take((size_t)N_NODES * 4);
  float*          v3    = (float*)take((size_t)N_NODES * 4);
  float*          v6    = (float*)take((size_t)N_NODES * 4);
  unsigned short* ell   = (unsigned short*)take((size_t)N_NODES * ELL_W * 2); // 6.4 MB
  float*          well  = (float*)take((size_t)N_NODES * ELL_W * 4);          // 12.8 MB
  float*          hA    = (float*)take((size_t)N_NODES * F_PAD * 4);          // 12.8 MB
  float*          hB    = (float*)take((size_t)N_NODES * F_PAD * 4);          // 12.8 MB
  float*          Mw    = (float*)take((size_t)F_IN * F_OUT * 4);
  float*          c1    = (float*)take((size_t)F_OUT * 4);
  float*          c2    = (float*)take((size_t)F_OUT * 4);
  float*          c3    = (float*)take((size_t)F_OUT * 4);

  (void)hipMemsetAsync(cnt, 0, (size_t)N_NODES * 4, stream);
  k_fill<<<(N_EDGES + 255) / 256, 256, 0, stream>>>(ei, cnt, ell);
  k_dinv<<<(N_NODES + 255) / 256, 256, 0, stream>>>(cnt, dinv, deg, ell);
  k_wfill<<<(N_NODES * ELL_W) / 256, 256, 0, stream>>>(deg, ell, dinv, well);
  k_loadx<<<(N_NODES * F_PAD) / 256, 256, 0, stream>>>(x, hA);
  k_weights<<<F_IN + 1, 256, 0, stream>>>(W1, b1, W2, b2, W3, b3, W4, b4, Mw, c1, c2, c3);

  // slice-major: 4 independent 16-feature chains, 9 hops each (L2-resident)
  for (int s = 0; s < 4; ++s) {
    float* src = hA + (size_t)s * NSLICE;
    float* dst = hB + (size_t)s * NSLICE;
    for (int hop = 1; hop <= 9; ++hop) {
      float* vs = (s == 3 && hop == 3) ? v3 : (s == 3 && hop == 6) ? v6 : nullptr;
      k_hop<<<(N_NODES * 16) / 256, 256, 0, stream>>>(src, dst, deg, ell, well, vs);
      float* t = src; src = dst; dst = t;
    }
    // 9 swaps: slice result ends in hB + s*NSLICE
  }
  k_final<<<(N_NODES + NB - 1) / NB, 256, 0, stream>>>(hB, v3, v6, Mw, c1, c2, c3, out);
}

// Round 7
// 386.100 us; speedup vs baseline: 1.9469x; 1.9469x over previous
//
#include <hip/hip_runtime.h>

#define N_NODES 50000
#define N_EDGES 800000
#define F_IN 56
#define F_PAD 64
#define F_OUT 256
#define NB 64      // nodes per k_final block
#define ELL_W 64   // slots per node; deg+1 max ~37 for Poisson(16)

// ---- fill: degree count + ELL placement in ONE atomic pass ----------------

__global__ void k_fill(const int* __restrict__ ei, int* __restrict__ cnt,
                       int* __restrict__ ell) {
  int e = blockIdx.x * blockDim.x + threadIdx.x;
  if (e >= N_EDGES) return;
  int s = ei[e];
  int d = ei[N_EDGES + e];
  int pos = atomicAdd(&cnt[d], 1);
  ell[(d << 6) + pos] = s;
}

// ---- dinv + deg + self-loop slot -------------------------------------------

__global__ void k_dinv(const int* __restrict__ cnt, float* __restrict__ dinv,
                       int* __restrict__ deg, int* __restrict__ ell) {
  int i = blockIdx.x * blockDim.x + threadIdx.x;
  if (i >= N_NODES) return;
  int c = cnt[i];
  dinv[i] = rsqrtf((float)(c + 1));
  deg[i] = c + 1;
  ell[(i << 6) + c] = i;  // self loop in last used slot
}

// ---- feature init: x padded to 64 cols, ones-vector in col 56 -------------

__global__ void k_loadx(const float* __restrict__ x, float* __restrict__ h) {
  int i = blockIdx.x * blockDim.x + threadIdx.x;  // N*64 threads
  int nn = i >> 6, f = i & 63;
  float v = 0.f;
  if (f < F_IN) v = x[nn * F_IN + f];
  else if (f == F_IN) v = 1.f;
  h[i] = v;
}

// ---- one hop: wave per node, 4 edge-rows per dwordx4 gather ---------------
// lane = (edge subgroup: lane>>4) x (feature quad: (lane&15)*4)

__global__ __launch_bounds__(256) void k_hop(const float* __restrict__ hin,
                                             float* __restrict__ hout,
                                             const int* __restrict__ deg,
                                             const int* __restrict__ ell,
                                             const float* __restrict__ dinv,
                                             float* __restrict__ vsave) {
  int node = (blockIdx.x * blockDim.x + threadIdx.x) >> 6;
  int lane = threadIdx.x & 63;
  int d = __builtin_amdgcn_readfirstlane(deg[node]);  // includes self loop, >=1
  int rec = ell[((size_t)node << 6) + lane];          // one coalesced 256B row load
  rec = (lane < d) ? rec : node;                      // safe address for pad slots
  float dn = __int_as_float(__builtin_amdgcn_readfirstlane(
      __float_as_int(dinv[node])));
  float wl = (lane < d) ? dinv[rec] * dn : 0.f;       // pad slots weight 0

  int sub = lane >> 4;          // which of the 4 edges this lane serves
  int fo  = (lane & 15) << 2;   // feature offset within row (0,4,...,60)
  float4 acc = make_float4(0.f, 0.f, 0.f, 0.f);

  int ngroups = (d + 3) >> 2;   // groups of 4 edges (zero-weight padded)
  int g = 0;
  for (; g + 2 <= ngroups; g += 2) {
    int   s0 = __shfl(rec, g * 4 + sub);
    float w0 = __shfl(wl,  g * 4 + sub);
    int   s1 = __shfl(rec, g * 4 + 4 + sub);
    float w1 = __shfl(wl,  g * 4 + 4 + sub);
    float4 a0 = *(const float4*)(hin + (((size_t)s0) << 6) + fo);
    float4 a1 = *(const float4*)(hin + (((size_t)s1) << 6) + fo);
    acc.x = fmaf(w0, a0.x, acc.x);
    acc.y = fmaf(w0, a0.y, acc.y);
    acc.z = fmaf(w0, a0.z, acc.z);
    acc.w = fmaf(w0, a0.w, acc.w);
    acc.x = fmaf(w1, a1.x, acc.x);
    acc.y = fmaf(w1, a1.y, acc.y);
    acc.z = fmaf(w1, a1.z, acc.z);
    acc.w = fmaf(w1, a1.w, acc.w);
  }
  if (g < ngroups) {
    int   s0 = __shfl(rec, g * 4 + sub);
    float w0 = __shfl(wl,  g * 4 + sub);
    float4 a0 = *(const float4*)(hin + (((size_t)s0) << 6) + fo);
    acc.x = fmaf(w0, a0.x, acc.x);
    acc.y = fmaf(w0, a0.y, acc.y);
    acc.z = fmaf(w0, a0.z, acc.z);
    acc.w = fmaf(w0, a0.w, acc.w);
  }
  // reduce the 4 edge subgroups (lanes l, l^16, l^32, l^48)
  acc.x += __shfl_xor(acc.x, 16);
  acc.y += __shfl_xor(acc.y, 16);
  acc.z += __shfl_xor(acc.z, 16);
  acc.w += __shfl_xor(acc.w, 16);
  acc.x += __shfl_xor(acc.x, 32);
  acc.y += __shfl_xor(acc.y, 32);
  acc.z += __shfl_xor(acc.z, 32);
  acc.w += __shfl_xor(acc.w, 32);

  if (lane < 16) {
    *(float4*)(hout + ((size_t)node << 6) + fo) = acc;
  }
  if (vsave != nullptr && lane == 14) vsave[node] = acc.x;  // feature 56 = A^k·1
}

// ---- collapse weights: M = W1W2W3W4; c1=b1'W2W3W4; c2=b2'W3W4; c3=b3'W4+b4

__global__ void k_weights(const float* __restrict__ W1, const float* __restrict__ b1,
                          const float* __restrict__ W2, const float* __restrict__ b2,
                          const float* __restrict__ W3, const float* __restrict__ b3,
                          const float* __restrict__ W4, const float* __restrict__ b4,
                          float* __restrict__ Mw, float* __restrict__ c1,
                          float* __restrict__ c2, float* __restrict__ c3) {
  __shared__ float t1[64], t2[64], t3[64];
  int m = blockIdx.x, tid = threadIdx.x;
  if (m < F_IN) {  // row m of M: ((W1[m,:]W2)W3)W4
    if (tid < 64) {
      float a = 0.f;
      for (int k = 0; k < 64; ++k) a = fmaf(W1[m * 64 + k], W2[k * 64 + tid], a);
      t1[tid] = a;
    }
    __syncthreads();
    if (tid < 64) {
      float a = 0.f;
      for (int k = 0; k < 64; ++k) a = fmaf(t1[k], W3[k * 64 + tid], a);
      t2[tid] = a;
    }
    __syncthreads();
    {
      float a = 0.f;
      for (int k = 0; k < 64; ++k) a = fmaf(t2[k], W4[k * 256 + tid], a);
      Mw[m * 256 + tid] = a;
    }
  } else {  // bias chains
    if (tid < 64) {
      float a = 0.f;
      for (int k = 0; k < 64; ++k) a = fmaf(b1[k], W2[k * 64 + tid], a);
      t1[tid] = a;
    }
    __syncthreads();
    if (tid < 64) {
      float a = 0.f, b = 0.f;
      for (int k = 0; k < 64; ++k) {
        float w3 = W3[k * 64 + tid];
        a = fmaf(t1[k], w3, a);
        b = fmaf(b2[k], w3, b);
      }
      t2[tid] = a; t3[tid] = b;
    }
    __syncthreads();
    {
      float a = 0.f, b = 0.f, c = 0.f;
      for (int k = 0; k < 64; ++k) {
        float w4 = W4[k * 256 + tid];
        a = fmaf(t2[k], w4, a);
        b = fmaf(t3[k], w4, b);
        c = fmaf(b3[k], w4, c);
      }
      c1[tid] = a; c2[tid] = b; c3[tid] = c + b4[tid];
    }
  }
}

// ---- epilogue: out = y@M + v6*c1 + v3*c2 + c3 -----------------------------
// thread j owns output col j; M[:,j] in 56 registers; y rows broadcast via LDS

__global__ __launch_bounds__(256) void k_final(const float* __restrict__ y,
                                               const float* __restrict__ v3,
                                               const float* __restrict__ v6,
                                               const float* __restrict__ Mw,
                                               const float* __restrict__ c1,
                                               const float* __restrict__ c2,
                                               const float* __restrict__ c3,
                                               float* __restrict__ out) {
  __shared__ float4 yl[NB][16];          // 16.5 KB
  __shared__ float v3l[NB], v6l[NB];
  int tid = threadIdx.x;
  int j = tid;                           // output column

  float4 Mreg[14];                       // M[:, j] — 56 VGPRs
#pragma unroll
  for (int k4 = 0; k4 < 14; ++k4) {
    Mreg[k4].x = Mw[(k4 * 4 + 0) * F_OUT + j];
    Mreg[k4].y = Mw[(k4 * 4 + 1) * F_OUT + j];
    Mreg[k4].z = Mw[(k4 * 4 + 2) * F_OUT + j];
    Mreg[k4].w = Mw[(k4 * 4 + 3) * F_OUT + j];
  }
  float C1 = c1[j], C2 = c2[j], C3 = c3[j];

  int n0 = blockIdx.x * NB;
  int lim = min(NB, N_NODES - n0);
  for (int i = tid; i < lim * 16; i += 256) {
    int nn = i >> 4, q = i & 15;
    yl[nn][q] = *(const float4*)(y + ((size_t)(n0 + nn) << 6) + q * 4);
  }
  if (tid < lim) { v3l[tid] = v3[n0 + tid]; v6l[tid] = v6[n0 + tid]; }
  __syncthreads();

  for (int nn = 0; nn < lim; ++nn) {
    float acc = fmaf(v6l[nn], C1, fmaf(v3l[nn], C2, C3));
#pragma unroll
    for (int k4 = 0; k4 < 14; ++k4) {
      float4 yv = yl[nn][k4];
      acc = fmaf(yv.x, Mreg[k4].x, acc);
      acc = fmaf(yv.y, Mreg[k4].y, acc);
      acc = fmaf(yv.z, Mreg[k4].z, acc);
      acc = fmaf(yv.w, Mreg[k4].w, acc);
    }
    out[(size_t)(n0 + nn) * F_OUT + j] = acc;
  }
}

// ---- launch ---------------------------------------------------------------

extern "C" void kernel_launch(void* const* d_in, const int* in_sizes, int n_in,
                              void* d_out, int out_size, void* d_ws, size_t ws_size,
                              hipStream_t stream) {
  const float* x  = (const float*)d_in[0];
  const int*   ei = (const int*)d_in[1];
  const float* W1 = (const float*)d_in[2];
  const float* b1 = (const float*)d_in[3];
  const float* W2 = (const float*)d_in[4];
  const float* b2 = (const float*)d_in[5];
  const float* W3 = (const float*)d_in[6];
  const float* b3 = (const float*)d_in[7];
  const float* W4 = (const float*)d_in[8];
  const float* b4 = (const float*)d_in[9];
  float* out = (float*)d_out;

  char* ws = (char*)d_ws;
  size_t off = 0;
  auto take = [&](size_t bytes) -> void* {
    void* p = ws + off;
    off += (bytes + 255) & ~(size_t)255;
    return p;
  };
  int*   cnt   = (int*)take((size_t)N_NODES * 4);
  int*   deg   = (int*)take((size_t)N_NODES * 4);
  float* dinv  = (float*)take((size_t)N_NODES * 4);
  float* v3    = (float*)take((size_t)N_NODES * 4);
  float* v6    = (float*)take((size_t)N_NODES * 4);
  int*   ell   = (int*)take((size_t)N_NODES * ELL_W * 4);   // 12.8 MB
  float* hA    = (float*)take((size_t)N_NODES * F_PAD * 4); // 12.8 MB
  float* hB    = (float*)take((size_t)N_NODES * F_PAD * 4); // 12.8 MB
  float* Mw    = (float*)take((size_t)F_IN * F_OUT * 4);
  float* c1    = (float*)take((size_t)F_OUT * 4);
  float* c2    = (float*)take((size_t)F_OUT * 4);
  float* c3    = (float*)take((size_t)F_OUT * 4);

  (void)hipMemsetAsync(cnt, 0, (size_t)N_NODES * 4, stream);
  k_fill<<<(N_EDGES + 255) / 256, 256, 0, stream>>>(ei, cnt, ell);
  k_dinv<<<(N_NODES + 255) / 256, 256, 0, stream>>>(cnt, dinv, deg, ell);
  k_loadx<<<(N_NODES * F_PAD) / 256, 256, 0, stream>>>(x, hA);
  k_weights<<<F_IN + 1, 256, 0, stream>>>(W1, b1, W2, b2, W3, b3, W4, b4, Mw, c1, c2, c3);

  float* src = hA;
  float* dst = hB;
  for (int hop = 1; hop <= 9; ++hop) {
    float* vs = (hop == 3) ? v3 : (hop == 6) ? v6 : nullptr;
    k_hop<<<(N_NODES * F_PAD) / 256, 256, 0, stream>>>(src, dst, deg, ell, dinv, vs);
    float* t = src; src = dst; dst = t;
  }
  k_final<<<(N_NODES + NB - 1) / NB, 256, 0, stream>>>(src, v3, v6, Mw, c1, c2, c3, out);
}